// Round 1
// baseline (19924.008 us; speedup 1.0000x reference)
//
#include <hip/hip_runtime.h>
#include <hip/hip_bf16.h>

#define BATCH 64
#define SEQ   2048
#define DIN   64
#define HID   256
#define G4H   1024
#define NCLS  8

__device__ __forceinline__ float sigm(float x)  { return 1.0f / (1.0f + __expf(-x)); }
__device__ __forceinline__ float tanh_f(float x){ return 1.0f - 2.0f / (__expf(2.0f * x) + 1.0f); }

// ---------------------------------------------------------------------------
// init: out[b][t][c] = bfc[c]  (positions beyond length keep exactly this)
// ---------------------------------------------------------------------------
__global__ void init_out_kernel(float* __restrict__ out, const float* __restrict__ bfc) {
    int idx = blockIdx.x * blockDim.x + threadIdx.x;
    if (idx < BATCH * SEQ * NCLS) out[idx] = bfc[idx & 7];
}

// ---------------------------------------------------------------------------
// Pass A: layer-0 LSTM. 256 blocks = 4 members x 64 batches.
// blockIdx = mem*64 + b  (members of a batch land on the same XCD mod 8).
// Each block owns 256 gate rows (j in [mem*64, mem*64+64) for each of i,f,g,o),
// weights [256 rows x 320 cols] in registers (80 f32/thread, 1024 threads).
// Publishes h1[t] chunk into hist (ws) with AGENT atomics + flag = t+1.
// ---------------------------------------------------------------------------
__global__ __launch_bounds__(1024) void lstm_l0_kernel(
    const float* __restrict__ x,    const float* __restrict__ Wih0,
    const float* __restrict__ Whh0, const float* __restrict__ bih0,
    const float* __restrict__ bhh0, float* __restrict__ hist,
    const float* __restrict__ h1s_in, float* __restrict__ h1s_out,
    float* __restrict__ c1s, int* __restrict__ flagsA, int t0, int t1)
{
    const int bx  = blockIdx.x;
    const int b   = bx & 63;
    const int mem = bx >> 6;          // 0..3
    const int tid = threadIdx.x;
    const int p   = tid >> 8;         // 0..3  width-quarter
    const int r   = tid & 255;        // 0..255 local row
    const int row = (r >> 6) * 256 + mem * 64 + (r & 63);

    float w[80];
#pragma unroll
    for (int q = 0; q < 80; ++q) {
        int col = p * 80 + q;
        w[q] = (col < DIN) ? Wih0[row * DIN + col] : Whh0[row * HID + (col - DIN)];
    }
    float biasv = 0.f;
    if (tid < 256) {
        int row2 = (tid >> 6) * 256 + mem * 64 + (tid & 63);
        biasv = bih0[row2] + bhh0[row2];
    }
    float creg = 0.f;
    if (tid < 64) creg = c1s[b * HID + mem * 64 + tid];

    __shared__ __align__(16) float v[320];     // x_t (64) | h1_{t-1} (256)
    __shared__ float pbuf[1024];
    __shared__ float act[256];

    for (int t = t0; t < t1; ++t) {
        if (t > t0 && tid < 4) {
            while (__hip_atomic_load(&flagsA[b * 4 + tid], __ATOMIC_ACQUIRE,
                                     __HIP_MEMORY_SCOPE_AGENT) < t) {}
        }
        __syncthreads();
        if (tid < 64) {
            v[tid] = x[((size_t)b * SEQ + t) * DIN + tid];
        } else if (tid < 320) {
            int j = tid - 64;
            v[tid] = (t == t0)
                ? h1s_in[b * HID + j]
                : __hip_atomic_load(&hist[((size_t)(t - 1 - t0) * BATCH + b) * HID + j],
                                    __ATOMIC_RELAXED, __HIP_MEMORY_SCOPE_AGENT);
        }
        __syncthreads();

        float a0 = 0.f, a1 = 0.f, a2 = 0.f, a3 = 0.f;
#pragma unroll
        for (int qq = 0; qq < 20; ++qq) {
            float4 vv = *(const float4*)&v[p * 80 + qq * 4];   // wave-uniform: LDS broadcast
            a0 = fmaf(w[qq * 4 + 0], vv.x, a0);
            a1 = fmaf(w[qq * 4 + 1], vv.y, a1);
            a2 = fmaf(w[qq * 4 + 2], vv.z, a2);
            a3 = fmaf(w[qq * 4 + 3], vv.w, a3);
        }
        pbuf[tid] = (a0 + a1) + (a2 + a3);
        __syncthreads();

        if (tid < 256) {
            float s = pbuf[tid] + pbuf[256 + tid] + pbuf[512 + tid] + pbuf[768 + tid] + biasv;
            act[tid] = ((tid >> 6) == 2) ? tanh_f(s) : sigm(s);
        }
        __syncthreads();

        if (tid < 64) {
            float iv = act[tid], fv = act[64 + tid], gv = act[128 + tid], ov = act[192 + tid];
            creg = fv * creg + iv * gv;
            float h = ov * tanh_f(creg);
            __hip_atomic_store(&hist[((size_t)(t - t0) * BATCH + b) * HID + mem * 64 + tid],
                               h, __ATOMIC_RELAXED, __HIP_MEMORY_SCOPE_AGENT);
            if (t == t1 - 1) {
                h1s_out[b * HID + mem * 64 + tid] = h;
                c1s[b * HID + mem * 64 + tid]     = creg;
            }
        }
        __syncthreads();   // compiler drains vmcnt(0) before s_barrier -> stores visible
        if (tid == 0) {
            __hip_atomic_store(&flagsA[b * 4 + mem], t + 1, __ATOMIC_RELEASE,
                               __HIP_MEMORY_SCOPE_AGENT);
        }
    }
}

// ---------------------------------------------------------------------------
// Pass B: layer-1 LSTM + masked FC. 256 blocks = 8 members x 32 batch-pairs.
// blockIdx = mem*32 + bp. Gates = [Wih1 | Whh1] @ [h1[t] | h2[t-1]] (width 512).
// Each block owns 128 gate rows (j in [mem*32, mem*32+32) x 4 gates) for BOTH
// batches of the pair (weights shared: 64 f32/thread). h2 exchanged via
// parity-double-buffered xbuf + flags. Emissions accumulated via atomicAdd.
// ---------------------------------------------------------------------------
__global__ __launch_bounds__(1024) void lstm_l1_kernel(
    const float* __restrict__ hist, const float* __restrict__ Wih1,
    const float* __restrict__ Whh1, const float* __restrict__ bih1,
    const float* __restrict__ bhh1, const float* __restrict__ Wfc,
    const int* __restrict__ lengths, float* __restrict__ out,
    const float* __restrict__ h2s_in, float* __restrict__ h2s_out,
    float* __restrict__ c2s, float* __restrict__ xbuf,
    int* __restrict__ flagsB, int t0, int t1)
{
    const int bx  = blockIdx.x;
    const int bp  = bx & 31;
    const int mem = bx >> 5;          // 0..7
    const int tid = threadIdx.x;
    const int p   = tid >> 7;         // 0..7 width-eighth
    const int r   = tid & 127;        // 0..127 local row
    const int row = (r >> 5) * 256 + mem * 32 + (r & 31);

    float w[64];
#pragma unroll
    for (int q = 0; q < 64; ++q) {
        int col = p * 64 + q;
        w[q] = (col < HID) ? Wih1[row * HID + col] : Whh1[row * HID + (col - HID)];
    }
    float biasv = 0.f;
    if (tid < 256) {
        int rr = tid & 127;
        int row2 = (rr >> 5) * 256 + mem * 32 + (rr & 31);
        biasv = bih1[row2] + bhh1[row2];
    }
    float creg = 0.f;
    if (tid < 64) {
        int n = tid >> 5, j2 = tid & 31;
        creg = c2s[(bp * 2 + n) * HID + mem * 32 + j2];
    }
    float wfc_r = 0.f; int mylen = 0;
    if (tid < 512) {
        int n = tid >> 8, c = (tid >> 5) & 7, j3 = tid & 31;
        wfc_r = Wfc[c * HID + mem * 32 + j3];
        mylen = lengths[bp * 2 + n];
    }

    __shared__ __align__(16) float vbuf[1024];  // [n][ h1(256) | h2prev(256) ]
    __shared__ float pbuf[2048];                // [n][p][r]
    __shared__ float act[256];                  // [n][128]
    __shared__ float hloc[64];                  // [n][32]

    for (int t = t0; t < t1; ++t) {
        if (t > t0 && tid < 8) {
            while (__hip_atomic_load(&flagsB[bp * 8 + tid], __ATOMIC_ACQUIRE,
                                     __HIP_MEMORY_SCOPE_AGENT) < t) {}
        }
        __syncthreads();
        if (tid < 512) {
            int n = tid >> 8, j = tid & 255;
            float hv = (t == t0)
                ? h2s_in[(bp * 2 + n) * HID + j]
                : __hip_atomic_load(&xbuf[((bp * 2 + n) * 2 + ((t - 1) & 1)) * HID + j],
                                    __ATOMIC_RELAXED, __HIP_MEMORY_SCOPE_AGENT);
            vbuf[n * 512 + HID + j] = hv;
        } else {
            int k = tid - 512;
            int n = k >> 8, j = k & 255;
            vbuf[n * 512 + j] = hist[((size_t)(t - t0) * BATCH + (bp * 2 + n)) * HID + j];
        }
        __syncthreads();

        float acc0 = 0.f, acc1 = 0.f;
#pragma unroll
        for (int qq = 0; qq < 16; ++qq) {
            float4 va = *(const float4*)&vbuf[p * 64 + qq * 4];
            acc0 = fmaf(w[qq * 4 + 0], va.x, acc0);
            acc0 = fmaf(w[qq * 4 + 1], va.y, acc0);
            acc0 = fmaf(w[qq * 4 + 2], va.z, acc0);
            acc0 = fmaf(w[qq * 4 + 3], va.w, acc0);
            float4 vb = *(const float4*)&vbuf[512 + p * 64 + qq * 4];
            acc1 = fmaf(w[qq * 4 + 0], vb.x, acc1);
            acc1 = fmaf(w[qq * 4 + 1], vb.y, acc1);
            acc1 = fmaf(w[qq * 4 + 2], vb.z, acc1);
            acc1 = fmaf(w[qq * 4 + 3], vb.w, acc1);
        }
        pbuf[p * 128 + r]        = acc0;
        pbuf[1024 + p * 128 + r] = acc1;
        __syncthreads();

        if (tid < 256) {
            int n = tid >> 7, rr = tid & 127;
            float s = biasv;
#pragma unroll
            for (int q = 0; q < 8; ++q) s += pbuf[n * 1024 + q * 128 + rr];
            act[n * 128 + rr] = ((rr >> 5) == 2) ? tanh_f(s) : sigm(s);
        }
        __syncthreads();

        if (tid < 64) {
            int n = tid >> 5, j2 = tid & 31;
            float iv = act[n * 128 + j2],      fv = act[n * 128 + 32 + j2];
            float gv = act[n * 128 + 64 + j2], ov = act[n * 128 + 96 + j2];
            creg = fv * creg + iv * gv;
            float h = ov * tanh_f(creg);
            hloc[tid] = h;
            __hip_atomic_store(&xbuf[((bp * 2 + n) * 2 + (t & 1)) * HID + mem * 32 + j2],
                               h, __ATOMIC_RELAXED, __HIP_MEMORY_SCOPE_AGENT);
            if (t == t1 - 1) {
                h2s_out[(bp * 2 + n) * HID + mem * 32 + j2] = h;
                c2s[(bp * 2 + n) * HID + mem * 32 + j2]     = creg;
            }
        }
        __syncthreads();   // drain xbuf stores before flag
        if (tid == 0) {
            __hip_atomic_store(&flagsB[bp * 8 + mem], t + 1, __ATOMIC_RELEASE,
                               __HIP_MEMORY_SCOPE_AGENT);
        }
        // emissions partial for this block's 32-wide h2 chunk (after sync: hloc valid)
        if (tid < 512) {
            int n = tid >> 8, c = (tid >> 5) & 7, j3 = tid & 31;
            float val = (t < mylen) ? hloc[n * 32 + j3] * wfc_r : 0.f;
            val += __shfl_xor(val, 1);
            val += __shfl_xor(val, 2);
            val += __shfl_xor(val, 4);
            val += __shfl_xor(val, 8);
            val += __shfl_xor(val, 16);
            if (j3 == 0)
                atomicAdd(&out[((size_t)(bp * 2 + n) * SEQ + t) * NCLS + c], val);
        }
    }
}

// ---------------------------------------------------------------------------
extern "C" void kernel_launch(void* const* d_in, const int* in_sizes, int n_in,
                              void* d_out, int out_size, void* d_ws, size_t ws_size,
                              hipStream_t stream) {
    (void)in_sizes; (void)n_in; (void)out_size;
    const float* x     = (const float*)d_in[0];
    const int*   lens  = (const int*)  d_in[1];
    const float* Wih0  = (const float*)d_in[2];
    const float* Whh0  = (const float*)d_in[3];
    const float* bih0  = (const float*)d_in[4];
    const float* bhh0  = (const float*)d_in[5];
    const float* Wih1  = (const float*)d_in[6];
    const float* Whh1  = (const float*)d_in[7];
    const float* bih1  = (const float*)d_in[8];
    const float* bhh1  = (const float*)d_in[9];
    const float* Wfc   = (const float*)d_in[10];
    const float* bfc   = (const float*)d_in[11];
    float* out = (float*)d_out;
    char*  ws  = (char*)d_ws;

    // workspace layout
    int*   flagsA = (int*)(ws + 0);                    // 1 KB (64*4 ints)
    int*   flagsB = (int*)(ws + 1024);                 // 1 KB (32*8 ints)
    float* h1sA   = (float*)(ws + 2048);               // 64 KB each
    float* h1sB   = (float*)(ws + 2048 + 1 * 65536);
    float* c1s    = (float*)(ws + 2048 + 2 * 65536);
    float* h2sA   = (float*)(ws + 2048 + 3 * 65536);
    float* h2sB   = (float*)(ws + 2048 + 4 * 65536);
    float* c2s    = (float*)(ws + 2048 + 5 * 65536);
    float* xbuf   = (float*)(ws + 2048 + 6 * 65536);   // 128 KB
    size_t hist_off = 2048 + 6 * 65536 + 131072;
    hist_off = (hist_off + 255) & ~(size_t)255;
    float* hist = (float*)(ws + hist_off);

    const size_t step_bytes = (size_t)BATCH * HID * 4;   // 64 KB per step of h1 history
    if (ws_size < hist_off + step_bytes) return;         // cannot run; fail loudly
    long avail = (long)(ws_size - hist_off);
    int Tc = (int)(avail / (long)step_bytes);
    if (Tc > SEQ) Tc = SEQ;
    if (Tc < 1)  Tc = 1;

    hipMemsetAsync(ws, 0, hist_off, stream);   // zero flags + states (+xbuf, harmless)
    init_out_kernel<<<(BATCH * SEQ * NCLS + 255) / 256, 256, 0, stream>>>(out, bfc);

    int flip = 0;
    for (int t0 = 0; t0 < SEQ; t0 += Tc) {
        int t1 = t0 + Tc; if (t1 > SEQ) t1 = SEQ;
        float* h1in  = flip ? h1sB : h1sA;
        float* h1out = flip ? h1sA : h1sB;
        float* h2in  = flip ? h2sB : h2sA;
        float* h2out = flip ? h2sA : h2sB;
        lstm_l0_kernel<<<256, 1024, 0, stream>>>(x, Wih0, Whh0, bih0, bhh0, hist,
                                                 h1in, h1out, c1s, flagsA, t0, t1);
        lstm_l1_kernel<<<256, 1024, 0, stream>>>(hist, Wih1, Whh1, bih1, bhh1, Wfc,
                                                 lens, out, h2in, h2out, c2s, xbuf,
                                                 flagsB, t0, t1);
        flip ^= 1;
    }
}